// Round 2
// baseline (1552.299 us; speedup 1.0000x reference)
//
#include <hip/hip_runtime.h>

using short8 = __attribute__((ext_vector_type(8))) short;
using f32x4  = __attribute__((ext_vector_type(4))) float;
using fvec4  = __attribute__((ext_vector_type(4))) float;

__device__ inline unsigned short f2bf(float x) {
  unsigned int u = __float_as_uint(x);
  unsigned int r = (u + 0x7FFFu + ((u >> 16) & 1u)) >> 16;
  return (unsigned short)r;
}
__device__ inline float bf2f(unsigned short s) {
  return __uint_as_float(((unsigned int)s) << 16);
}
__device__ inline short8 cvt8(fvec4 a, fvec4 b) {
  short8 r;
#pragma unroll
  for (int i = 0; i < 4; ++i) { r[i] = (short)f2bf(a[i]); r[i + 4] = (short)f2bf(b[i]); }
  return r;
}

// B fragments for [64x64] W (row-major f32): lane holds B[k=ks*32+lh*8+i][col=ct*16+l15]
__device__ inline void load_bfrags(const float* __restrict__ W, short8 bfr[2][4], int lane) {
  int l15 = lane & 15, lh = lane >> 4;
#pragma unroll
  for (int ks = 0; ks < 2; ++ks)
#pragma unroll
    for (int ct = 0; ct < 4; ++ct) {
      short8 v;
#pragma unroll
      for (int i = 0; i < 8; ++i)
        v[i] = (short)f2bf(W[(ks * 32 + lh * 8 + i) * 64 + ct * 16 + l15]);
      bfr[ks][ct] = v;
    }
}

struct ProjArgs {
  const float* W[6];
  unsigned short* out[6];
};

// all 6 projections of h in one pass (read h once)
__global__ __launch_bounds__(256) void proj_all_kernel(const float* __restrict__ h, ProjArgs pa, int N) {
  int lane = threadIdx.x & 63;
  int wv = threadIdx.x >> 6;
  int rowbase = blockIdx.x * 256 + wv * 64;
  int l15 = lane & 15, lh = lane >> 4;

  short8 afr[4][2];
#pragma unroll
  for (int rt = 0; rt < 4; ++rt) {
    int row = rowbase + rt * 16 + l15;
    int rc = row < N ? row : 0;
    const fvec4* p = reinterpret_cast<const fvec4*>(h + (size_t)rc * 64);
#pragma unroll
    for (int ks = 0; ks < 2; ++ks)
      afr[rt][ks] = cvt8(p[ks * 8 + lh * 2], p[ks * 8 + lh * 2 + 1]);
  }

  for (int z = 0; z < 6; ++z) {
    short8 bfr[2][4];
    load_bfrags(pa.W[z], bfr, lane);
    unsigned short* __restrict__ out = pa.out[z];

    f32x4 acc[4][4];
#pragma unroll
    for (int rt = 0; rt < 4; ++rt)
#pragma unroll
      for (int ct = 0; ct < 4; ++ct) acc[rt][ct] = (f32x4){0.f, 0.f, 0.f, 0.f};

#pragma unroll
    for (int rt = 0; rt < 4; ++rt)
#pragma unroll
      for (int ks = 0; ks < 2; ++ks)
#pragma unroll
        for (int ct = 0; ct < 4; ++ct)
          acc[rt][ct] = __builtin_amdgcn_mfma_f32_16x16x32_bf16(afr[rt][ks], bfr[ks][ct], acc[rt][ct], 0, 0, 0);

#pragma unroll
    for (int rt = 0; rt < 4; ++rt)
#pragma unroll
      for (int rg = 0; rg < 4; ++rg) {
        int row = rowbase + rt * 16 + lh * 4 + rg;
        if (row < N) {
#pragma unroll
          for (int ct = 0; ct < 4; ++ct)
            out[(size_t)row * 64 + ct * 16 + l15] = f2bf(acc[rt][ct][rg]);
        }
      }
  }
}

// ---- counting sort by dst (both graphs in one launch series) ----
__global__ __launch_bounds__(256) void hist_kernel(const int* __restrict__ dst0, const int* __restrict__ dst1,
                                                   int* __restrict__ counts, int E, int N) {
  int i = blockIdx.x * 256 + threadIdx.x;
  if (i < 2 * E) {
    int z = i >= E;
    int idx = z ? i - E : i;
    int d = z ? dst1[idx] : dst0[idx];
    atomicAdd(&counts[(size_t)z * N + d], 1);
  }
}

__global__ __launch_bounds__(1024) void scan_kernel(const int* __restrict__ counts, int* __restrict__ cursor, int N) {
  int z = blockIdx.x;
  const int* c = counts + (size_t)z * N;
  int* cur = cursor + (size_t)z * N;
  __shared__ int lds[1024];
  int t = threadIdx.x;
  int carry = 0;
  for (int base = 0; base < N; base += 1024) {
    int i = base + t;
    int v = (i < N) ? c[i] : 0;
    lds[t] = v;
    __syncthreads();
    for (int off = 1; off < 1024; off <<= 1) {
      int x = (t >= off) ? lds[t - off] : 0;
      __syncthreads();
      lds[t] += x;
      __syncthreads();
    }
    int incl = lds[t];
    if (i < N) cur[i] = carry + incl - v;
    carry += lds[1023];
    __syncthreads();
  }
}

__global__ __launch_bounds__(256) void scatter_kernel(const int* __restrict__ dst0, const int* __restrict__ dst1,
                                                      int* __restrict__ cursor, int* __restrict__ el0,
                                                      int* __restrict__ el1, int E, int N) {
  int i = blockIdx.x * 256 + threadIdx.x;
  if (i < 2 * E) {
    int z = i >= E;
    int idx = z ? i - E : i;
    int d = z ? dst1[idx] : dst0[idx];
    int pos = atomicAdd(&cursor[(size_t)z * N + d], 1);
    (z ? el1 : el0)[pos] = idx;
  }
}

// ---- edge GEMM over dst-sorted tiles + in-wave segmented flush ----
__global__ __launch_bounds__(256) void edge_sorted_kernel(
    const float* __restrict__ e, const int* __restrict__ src, const int* __restrict__ dst,
    const int* __restrict__ elist, const float* __restrict__ W, const float* __restrict__ bmsg,
    const unsigned short* __restrict__ Psrc, const unsigned short* __restrict__ Pdst,
    float* __restrict__ agg, int E) {
  __shared__ short m_lds[4][64 * 66];
  __shared__ int el_lds[4][64];
  __shared__ int dl_lds[4][64];
  __shared__ int sl_lds[4][64];

  int lane = threadIdx.x & 63;
  int wv = threadIdx.x >> 6;
  int base = (blockIdx.x * 4 + wv) * 64;
  if (base >= E) return;  // no __syncthreads below; per-wave exit is safe
  int l15 = lane & 15, lh = lane >> 4;

  // load this wave's 64 sorted slots
  int slot = base + lane;
  int el, dl = -1, sl = 0;
  if (slot < E) {
    el = elist[slot];
    dl = dst[el];
    sl = src[el];
  } else {
    el = elist[E - 1];  // safe clamp for e-row gather; dl=-1 marks padding
  }
  el_lds[wv][lane] = el;
  dl_lds[wv][lane] = dl;
  sl_lds[wv][lane] = sl;

  short8 bfr[2][4];
  load_bfrags(W, bfr, lane);

  f32x4 acc[4][4];
#pragma unroll
  for (int rt = 0; rt < 4; ++rt)
#pragma unroll
    for (int ct = 0; ct < 4; ++ct) acc[rt][ct] = (f32x4){0.f, 0.f, 0.f, 0.f};

#pragma unroll
  for (int rt = 0; rt < 4; ++rt) {
    int er = el_lds[wv][rt * 16 + l15];
    const fvec4* pr = reinterpret_cast<const fvec4*>(e + (size_t)er * 64);
#pragma unroll
    for (int ks = 0; ks < 2; ++ks) {
      short8 a = cvt8(pr[ks * 8 + lh * 2], pr[ks * 8 + lh * 2 + 1]);
#pragma unroll
      for (int ct = 0; ct < 4; ++ct)
        acc[rt][ct] = __builtin_amdgcn_mfma_f32_16x16x32_bf16(a, bfr[ks][ct], acc[rt][ct], 0, 0, 0);
    }
  }

  float bv[4];
#pragma unroll
  for (int ct = 0; ct < 4; ++ct) bv[ct] = bmsg[ct * 16 + l15];

  // epilogue: add gathered projections + bias, relu, stash bf16 tile in LDS
#pragma unroll
  for (int rt = 0; rt < 4; ++rt)
#pragma unroll
    for (int rg = 0; rg < 4; ++rg) {
      int row = rt * 16 + lh * 4 + rg;
      int s = sl_lds[wv][row];
      int d0 = dl_lds[wv][row];
      int d = d0 < 0 ? 0 : d0;
      size_t sb = (size_t)s * 64, db = (size_t)d * 64;
#pragma unroll
      for (int ct = 0; ct < 4; ++ct) {
        int c = ct * 16 + l15;
        float v = acc[rt][ct][rg] + bf2f(Psrc[sb + c]) + bf2f(Pdst[db + c]) + bv[ct];
        m_lds[wv][row * 66 + c] = f2bf(fmaxf(v, 0.0f));
      }
    }

  // segmented column-sum over sorted dst; one atomic per (segment, col)
  const short* mb = &m_lds[wv][0];
  float racc = 0.f;
  int dcur = -1;
  for (int r = 0; r < 64; ++r) {
    int dr = dl_lds[wv][r];     // uniform across lanes
    if (dr < 0) break;          // padding tail (sorted => only at end)
    if (dr != dcur) {
      if (dcur >= 0) atomicAdd(&agg[(size_t)dcur * 64 + lane], racc);
      racc = 0.f;
      dcur = dr;
    }
    racc += bf2f((unsigned short)mb[r * 66 + lane]);
  }
  if (dcur >= 0) atomicAdd(&agg[(size_t)dcur * 64 + lane], racc);
}

struct NodeArgs {
  const float* agg[2];
  const unsigned short* T[2];
  const float* W[2];
  const float* bn[2];
  unsigned short* U[2];
};

// U = bf16(relu(T + agg@Wagg + b_node)); agg split hi+lo bf16 for accuracy
__global__ __launch_bounds__(256) void node_kernel(NodeArgs na, int N) {
  int z = blockIdx.y;
  const float* __restrict__ agg = na.agg[z];
  const unsigned short* __restrict__ T = na.T[z];
  const float* __restrict__ bn = na.bn[z];
  unsigned short* __restrict__ U = na.U[z];
  int lane = threadIdx.x & 63;
  int wv = threadIdx.x >> 6;
  int rowbase = blockIdx.x * 256 + wv * 64;
  int l15 = lane & 15, lh = lane >> 4;

  short8 bfr[2][4];
  load_bfrags(na.W[z], bfr, lane);

  f32x4 acc[4][4];
#pragma unroll
  for (int rt = 0; rt < 4; ++rt)
#pragma unroll
    for (int ct = 0; ct < 4; ++ct) acc[rt][ct] = (f32x4){0.f, 0.f, 0.f, 0.f};

#pragma unroll
  for (int rt = 0; rt < 4; ++rt) {
    int row = rowbase + rt * 16 + l15;
    int rc = row < N ? row : 0;
    const fvec4* p = reinterpret_cast<const fvec4*>(agg + (size_t)rc * 64);
#pragma unroll
    for (int ks = 0; ks < 2; ++ks) {
      fvec4 p0 = p[ks * 8 + lh * 2], p1 = p[ks * 8 + lh * 2 + 1];
      short8 ahi = cvt8(p0, p1);
      fvec4 q0, q1;
#pragma unroll
      for (int i = 0; i < 4; ++i) {
        q0[i] = p0[i] - bf2f((unsigned short)ahi[i]);
        q1[i] = p1[i] - bf2f((unsigned short)ahi[i + 4]);
      }
      short8 alo = cvt8(q0, q1);
#pragma unroll
      for (int ct = 0; ct < 4; ++ct) {
        acc[rt][ct] = __builtin_amdgcn_mfma_f32_16x16x32_bf16(ahi, bfr[ks][ct], acc[rt][ct], 0, 0, 0);
        acc[rt][ct] = __builtin_amdgcn_mfma_f32_16x16x32_bf16(alo, bfr[ks][ct], acc[rt][ct], 0, 0, 0);
      }
    }
  }

  float bv[4];
#pragma unroll
  for (int ct = 0; ct < 4; ++ct) bv[ct] = bn[ct * 16 + l15];

#pragma unroll
  for (int rt = 0; rt < 4; ++rt)
#pragma unroll
    for (int rg = 0; rg < 4; ++rg) {
      int row = rowbase + rt * 16 + lh * 4 + rg;
      if (row < N) {
#pragma unroll
        for (int ct = 0; ct < 4; ++ct) {
          int c = ct * 16 + l15;
          float v = acc[rt][ct][rg] + bf2f(T[(size_t)row * 64 + c]) + bv[ct];
          U[(size_t)row * 64 + c] = f2bf(fmaxf(v, 0.0f));
        }
      }
    }
}

// attention over the 2-way stack; 4 threads per node
__global__ __launch_bounds__(256) void attn_kernel(
    const unsigned short* __restrict__ U0, const unsigned short* __restrict__ U1,
    const float* __restrict__ l1w, const float* __restrict__ l1b, const float* __restrict__ l2w,
    float* __restrict__ out, int N) {
  int t = threadIdx.x;
  int node = blockIdx.x * 64 + (t >> 2);
  int q = t & 3;
  if (node >= N) return;
  size_t b0 = (size_t)node * 64;

  float a0[8], a1[8];
#pragma unroll
  for (int i = 0; i < 8; ++i) { a0[i] = l1b[q * 8 + i]; a1[i] = a0[i]; }

  for (int k = 0; k < 64; ++k) {
    float u0 = bf2f(U0[b0 + k]);
    float u1 = bf2f(U1[b0 + k]);
#pragma unroll
    for (int i = 0; i < 8; ++i) {
      float w = l1w[k * 32 + q * 8 + i];
      a0[i] += u0 * w;
      a1[i] += u1 * w;
    }
  }
  float w0 = 0.f, w1 = 0.f;
#pragma unroll
  for (int i = 0; i < 8; ++i) {
    float l2 = l2w[q * 8 + i];
    w0 += tanhf(a0[i]) * l2;
    w1 += tanhf(a1[i]) * l2;
  }
  w0 += __shfl_xor(w0, 1, 4); w0 += __shfl_xor(w0, 2, 4);
  w1 += __shfl_xor(w1, 1, 4); w1 += __shfl_xor(w1, 2, 4);

  float m = fmaxf(w0, w1);
  float e0 = expf(w0 - m), e1 = expf(w1 - m);
  float inv = 1.0f / (e0 + e1);
  float be0 = e0 * inv, be1 = e1 * inv;

#pragma unroll
  for (int j = 0; j < 16; ++j) {
    int c = q * 16 + j;
    out[b0 + c] = be0 * bf2f(U0[b0 + c]) + be1 * bf2f(U1[b0 + c]);
  }
}

static inline size_t au(size_t x) { return (x + 255) & ~(size_t)255; }

extern "C" void kernel_launch(void* const* d_in, const int* in_sizes, int n_in,
                              void* d_out, int out_size, void* d_ws, size_t ws_size,
                              hipStream_t stream) {
  const float* h      = (const float*)d_in[0];
  const float* e_od   = (const float*)d_in[1];
  const float* e_ad   = (const float*)d_in[2];
  const int* src_od   = (const int*)d_in[3];
  const int* dst_od   = (const int*)d_in[4];
  const int* src_ad   = (const int*)d_in[5];
  const int* dst_ad   = (const int*)d_in[6];
  const float* W_src  = (const float*)d_in[7];
  const float* W_dst  = (const float*)d_in[8];
  const float* W_edge = (const float*)d_in[9];
  const float* b_msg  = (const float*)d_in[10];
  const float* W_self = (const float*)d_in[11];
  const float* W_agg  = (const float*)d_in[12];
  const float* b_node = (const float*)d_in[13];
  const float* l1w    = (const float*)d_in[14];
  const float* l1b    = (const float*)d_in[15];
  const float* l2w    = (const float*)d_in[16];
  float* out = (float*)d_out;

  int N = in_sizes[0] / 64;
  int E = in_sizes[1] / 64;

  char* ws = (char*)d_ws;
  size_t off = 0;
  int* counts = (int*)(ws + off);           off += au((size_t)2 * N * sizeof(int));
  float* agg0 = (float*)(ws + off);         off += (size_t)N * 64 * sizeof(float);
  float* agg1 = (float*)(ws + off);         off += (size_t)N * 64 * sizeof(float);
  size_t zero_bytes = off;                  // counts + agg0 + agg1 contiguous
  int* cursor = (int*)(ws + off);           off += au((size_t)2 * N * sizeof(int));
  int* el0 = (int*)(ws + off);              off += au((size_t)E * sizeof(int));
  int* el1 = (int*)(ws + off);              off += au((size_t)E * sizeof(int));
  size_t NP = au((size_t)N * 64 * sizeof(unsigned short));
  unsigned short* Psrc0 = (unsigned short*)(ws + off); off += NP;
  unsigned short* Pdst0 = (unsigned short*)(ws + off); off += NP;
  unsigned short* Psrc1 = (unsigned short*)(ws + off); off += NP;
  unsigned short* Pdst1 = (unsigned short*)(ws + off); off += NP;
  unsigned short* T0    = (unsigned short*)(ws + off); off += NP;
  unsigned short* T1    = (unsigned short*)(ws + off); off += NP;
  unsigned short* U0 = Psrc0;  // dead after edge pass of graph 0
  unsigned short* U1 = Psrc1;  // dead after edge pass of graph 1

  hipMemsetAsync(ws, 0, zero_bytes, stream);

  int nb = (N + 255) / 256;
  ProjArgs pa;
  pa.W[0] = W_src;         pa.out[0] = Psrc0;
  pa.W[1] = W_dst;         pa.out[1] = Pdst0;
  pa.W[2] = W_src + 4096;  pa.out[2] = Psrc1;
  pa.W[3] = W_dst + 4096;  pa.out[3] = Pdst1;
  pa.W[4] = W_self;        pa.out[4] = T0;
  pa.W[5] = W_self + 4096; pa.out[5] = T1;
  proj_all_kernel<<<nb, 256, 0, stream>>>(h, pa, N);

  int g2e = (2 * E + 255) / 256;
  hist_kernel<<<g2e, 256, 0, stream>>>(dst_od, dst_ad, counts, E, N);
  scan_kernel<<<2, 1024, 0, stream>>>(counts, cursor, N);
  scatter_kernel<<<g2e, 256, 0, stream>>>(dst_od, dst_ad, cursor, el0, el1, E, N);

  int tiles = (E + 63) / 64;
  int eb = (tiles + 3) / 4;
  edge_sorted_kernel<<<eb, 256, 0, stream>>>(e_od, src_od, dst_od, el0, W_edge, b_msg,
                                             Psrc0, Pdst0, agg0, E);
  edge_sorted_kernel<<<eb, 256, 0, stream>>>(e_ad, src_ad, dst_ad, el1, W_edge + 4096, b_msg + 64,
                                             Psrc1, Pdst1, agg1, E);

  NodeArgs na;
  na.agg[0] = agg0; na.T[0] = T0; na.W[0] = W_agg;        na.bn[0] = b_node;      na.U[0] = U0;
  na.agg[1] = agg1; na.T[1] = T1; na.W[1] = W_agg + 4096; na.bn[1] = b_node + 64; na.U[1] = U1;
  node_kernel<<<dim3(nb, 2), 256, 0, stream>>>(na, N);

  attn_kernel<<<(N + 63) / 64, 256, 0, stream>>>(U0, U1, l1w, l1b, l2w, out, N);
}

// Round 3
// 958.624 us; speedup vs baseline: 1.6193x; 1.6193x over previous
//
#include <hip/hip_runtime.h>

using short8  = __attribute__((ext_vector_type(8))) short;
using ushort8 = __attribute__((ext_vector_type(8))) unsigned short;
using f32x4   = __attribute__((ext_vector_type(4))) float;
using fvec4   = __attribute__((ext_vector_type(4))) float;

__device__ inline unsigned short f2bf(float x) {
  unsigned int u = __float_as_uint(x);
  unsigned int r = (u + 0x7FFFu + ((u >> 16) & 1u)) >> 16;
  return (unsigned short)r;
}
__device__ inline float bf2f(unsigned short s) {
  return __uint_as_float(((unsigned int)s) << 16);
}
__device__ inline short8 cvt8(fvec4 a, fvec4 b) {
  short8 r;
#pragma unroll
  for (int i = 0; i < 4; ++i) { r[i] = (short)f2bf(a[i]); r[i + 4] = (short)f2bf(b[i]); }
  return r;
}

// B fragments for [64x64] W (row-major f32): lane holds B[k=ks*32+lh*8+i][col=ct*16+l15]
__device__ inline void load_bfrags(const float* __restrict__ W, short8 bfr[2][4], int lane) {
  int l15 = lane & 15, lh = lane >> 4;
#pragma unroll
  for (int ks = 0; ks < 2; ++ks)
#pragma unroll
    for (int ct = 0; ct < 4; ++ct) {
      short8 v;
#pragma unroll
      for (int i = 0; i < 8; ++i)
        v[i] = (short)f2bf(W[(ks * 32 + lh * 8 + i) * 64 + ct * 16 + l15]);
      bfr[ks][ct] = v;
    }
}

struct ProjArgs {
  const float* W[6];
  unsigned short* out[6];
};

// all 6 projections of h in one pass (read h once)
__global__ __launch_bounds__(256) void proj_all_kernel(const float* __restrict__ h, ProjArgs pa, int N) {
  int lane = threadIdx.x & 63;
  int wv = threadIdx.x >> 6;
  int rowbase = blockIdx.x * 256 + wv * 64;
  int l15 = lane & 15, lh = lane >> 4;

  short8 afr[4][2];
#pragma unroll
  for (int rt = 0; rt < 4; ++rt) {
    int row = rowbase + rt * 16 + l15;
    int rc = row < N ? row : 0;
    const fvec4* p = reinterpret_cast<const fvec4*>(h + (size_t)rc * 64);
#pragma unroll
    for (int ks = 0; ks < 2; ++ks)
      afr[rt][ks] = cvt8(p[ks * 8 + lh * 2], p[ks * 8 + lh * 2 + 1]);
  }

  for (int z = 0; z < 6; ++z) {
    short8 bfr[2][4];
    load_bfrags(pa.W[z], bfr, lane);
    unsigned short* __restrict__ out = pa.out[z];

    f32x4 acc[4][4];
#pragma unroll
    for (int rt = 0; rt < 4; ++rt)
#pragma unroll
      for (int ct = 0; ct < 4; ++ct) acc[rt][ct] = (f32x4){0.f, 0.f, 0.f, 0.f};

#pragma unroll
    for (int rt = 0; rt < 4; ++rt)
#pragma unroll
      for (int ks = 0; ks < 2; ++ks)
#pragma unroll
        for (int ct = 0; ct < 4; ++ct)
          acc[rt][ct] = __builtin_amdgcn_mfma_f32_16x16x32_bf16(afr[rt][ks], bfr[ks][ct], acc[rt][ct], 0, 0, 0);

#pragma unroll
    for (int rt = 0; rt < 4; ++rt)
#pragma unroll
      for (int rg = 0; rg < 4; ++rg) {
        int row = rowbase + rt * 16 + lh * 4 + rg;
        if (row < N) {
#pragma unroll
          for (int ct = 0; ct < 4; ++ct)
            out[(size_t)row * 64 + ct * 16 + l15] = f2bf(acc[rt][ct][rg]);
        }
      }
  }
}

// ---- counting sort by dst ----
__global__ __launch_bounds__(256) void hist_kernel(const int* __restrict__ dst0, const int* __restrict__ dst1,
                                                   int* __restrict__ counts, int E, int N) {
  int i = blockIdx.x * 256 + threadIdx.x;
  if (i < 2 * E) {
    int z = i >= E;
    int idx = z ? i - E : i;
    int d = z ? dst1[idx] : dst0[idx];
    atomicAdd(&counts[(size_t)z * N + d], 1);
  }
}

// parallel scan: per-1024-chunk block scan
__global__ __launch_bounds__(1024) void scan1_kernel(const int* __restrict__ counts, int* __restrict__ cursor,
                                                     int* __restrict__ bsum, int N, int NB) {
  int z = blockIdx.y;
  int t = threadIdx.x;
  int i = blockIdx.x * 1024 + t;
  __shared__ int lds[1024];
  int v = (i < N) ? counts[(size_t)z * N + i] : 0;
  lds[t] = v;
  __syncthreads();
  for (int off = 1; off < 1024; off <<= 1) {
    int x = (t >= off) ? lds[t - off] : 0;
    __syncthreads();
    lds[t] += x;
    __syncthreads();
  }
  if (i < N) cursor[(size_t)z * N + i] = lds[t] - v;  // exclusive
  if (t == 1023) bsum[z * NB + blockIdx.x] = lds[1023];
}

__global__ __launch_bounds__(1024) void scan2_kernel(int* __restrict__ bsum, int NB) {
  int z = blockIdx.x;
  int t = threadIdx.x;
  __shared__ int lds[1024];
  int v = (t < NB) ? bsum[z * NB + t] : 0;
  lds[t] = v;
  __syncthreads();
  for (int off = 1; off < 1024; off <<= 1) {
    int x = (t >= off) ? lds[t - off] : 0;
    __syncthreads();
    lds[t] += x;
    __syncthreads();
  }
  if (t < NB) bsum[z * NB + t] = lds[t] - v;  // exclusive block offsets
}

__global__ __launch_bounds__(256) void scan3_kernel(int* __restrict__ cursor, const int* __restrict__ bsum,
                                                    int N, int NB) {
  int z = blockIdx.y;
  int i = blockIdx.x * 256 + threadIdx.x;
  if (i < N) cursor[(size_t)z * N + i] += bsum[z * NB + i / 1024];
}

__global__ __launch_bounds__(256) void scatter_kernel(
    const int* __restrict__ src0, const int* __restrict__ dst0,
    const int* __restrict__ src1, const int* __restrict__ dst1,
    int* __restrict__ cursor, int* __restrict__ el0, int2* __restrict__ sd0,
    int* __restrict__ el1, int2* __restrict__ sd1, int E, int N) {
  int i = blockIdx.x * 256 + threadIdx.x;
  if (i < 2 * E) {
    int z = i >= E;
    int idx = z ? i - E : i;
    int d = z ? dst1[idx] : dst0[idx];
    int s = z ? src1[idx] : src0[idx];
    int pos = atomicAdd(&cursor[(size_t)z * N + d], 1);
    if (z) { el1[pos] = idx; sd1[pos] = make_int2(s, d); }
    else   { el0[pos] = idx; sd0[pos] = make_int2(s, d); }
  }
}

// ---- edge GEMM over dst-sorted tiles ----
// x = e@We + Psrc[src] + b  (bf16, staged in LDS); flush: agg[dst] += relu(x + Pdst[dst])
// with Pdst row loaded once per segment (dst constant within segment).
#define XST 72  // LDS row stride in shorts (144 B, 16B-aligned)
__global__ __launch_bounds__(256) void edge_sorted_kernel(
    const float* __restrict__ e, const int* __restrict__ el_arr, const int2* __restrict__ sd_arr,
    const float* __restrict__ W, const float* __restrict__ bmsg,
    const unsigned short* __restrict__ Psrc, const unsigned short* __restrict__ Pdst,
    float* __restrict__ agg, int E) {
  __shared__ unsigned short x_lds[4][64 * XST];

  int lane = threadIdx.x & 63;
  int wv = threadIdx.x >> 6;
  int base = (blockIdx.x * 4 + wv) * 64;
  if (base >= E) return;  // no barriers anywhere: per-wave exit is safe
  int l15 = lane & 15, lh = lane >> 4;
  unsigned short* xw = &x_lds[wv][0];

  // this wave's 64 sorted slots (coalesced, no dependent gathers)
  int slot = base + lane;
  int el = 0, sl = 0, dl = -1;
  if (slot < E) {
    el = el_arr[slot];
    int2 sd = sd_arr[slot];
    sl = sd.x;
    dl = sd.y;
  }

  // ---- Psrc gather: 8 wide dwordx4 instrs; lane covers row i*8+(lane>>3), chunk (lane&7)
  int myrow8 = lane >> 3, mychunk = lane & 7;
  ushort8 psv[8];
#pragma unroll
  for (int i = 0; i < 8; ++i) {
    int srow = __shfl(sl, i * 8 + myrow8);
    psv[i] = *reinterpret_cast<const ushort8*>(Psrc + ((size_t)srow << 6) + mychunk * 8);
  }
  // stage to LDS (releases psv registers before MFMA)
#pragma unroll
  for (int i = 0; i < 8; ++i)
    *reinterpret_cast<ushort8*>(xw + (i * 8 + myrow8) * XST + mychunk * 8) = psv[i];

  short8 bfr[2][4];
  load_bfrags(W, bfr, lane);

  f32x4 acc[4][4];
#pragma unroll
  for (int rt = 0; rt < 4; ++rt)
#pragma unroll
    for (int ct = 0; ct < 4; ++ct) acc[rt][ct] = (f32x4){0.f, 0.f, 0.f, 0.f};

#pragma unroll
  for (int rt = 0; rt < 4; ++rt) {
    int er = __shfl(el, rt * 16 + l15);
    const fvec4* pr = reinterpret_cast<const fvec4*>(e + ((size_t)er << 6));
#pragma unroll
    for (int ks = 0; ks < 2; ++ks) {
      short8 a = cvt8(pr[ks * 8 + lh * 2], pr[ks * 8 + lh * 2 + 1]);
#pragma unroll
      for (int ct = 0; ct < 4; ++ct)
        acc[rt][ct] = __builtin_amdgcn_mfma_f32_16x16x32_bf16(a, bfr[ks][ct], acc[rt][ct], 0, 0, 0);
    }
  }

  float bv[4];
#pragma unroll
  for (int ct = 0; ct < 4; ++ct) bv[ct] = bmsg[ct * 16 + l15];

  // order LDS: ps writes (above) complete & visible before epilogue reads (cross-lane)
  asm volatile("s_waitcnt lgkmcnt(0)" ::: "memory");
  __builtin_amdgcn_sched_barrier(0);

  // ---- epilogue: x = bf16(acc + ps + b), in place (no relu, no pd yet)
#pragma unroll
  for (int rt = 0; rt < 4; ++rt)
#pragma unroll
    for (int rg = 0; rg < 4; ++rg) {
      int row = rt * 16 + lh * 4 + rg;
#pragma unroll
      for (int ct = 0; ct < 4; ++ct) {
        int c = ct * 16 + l15;
        float v = acc[rt][ct][rg] + bf2f(xw[row * XST + c]) + bv[ct];
        xw[row * XST + c] = f2bf(v);
      }
    }

  asm volatile("s_waitcnt lgkmcnt(0)" ::: "memory");
  __builtin_amdgcn_sched_barrier(0);

  // ---- segmented flush: boundaries precomputed via ballot (SGPR mask)
  int dprev = __shfl_up(dl, 1);
  unsigned long long bnd = __ballot(lane > 0 && dl != dprev);

  float racc = 0.f, pdv = 0.f;
  int dcur = -1;
  for (int r = 0; r < 64; ++r) {
    bool newseg = (r == 0) || ((bnd >> r) & 1ull);
    if (newseg) {  // wave-uniform scalar branch
      if (dcur >= 0) atomicAdd(&agg[(size_t)dcur * 64 + lane], racc);
      dcur = __shfl(dl, r);
      if (dcur < 0) break;  // padding tail (sorted => only at end)
      racc = 0.f;
      pdv = bf2f(Pdst[(size_t)dcur * 64 + lane]);  // one 128B row per segment
    }
    float xv = bf2f(xw[r * XST + lane]);
    racc += fmaxf(xv + pdv, 0.f);
  }
  if (dcur >= 0) atomicAdd(&agg[(size_t)dcur * 64 + lane], racc);
}

struct NodeArgs {
  const float* agg[2];
  const unsigned short* T[2];
  const float* W[2];
  const float* bn[2];
  unsigned short* U[2];
};

// U = bf16(relu(T + agg@Wagg + b_node)); agg split hi+lo bf16 for accuracy
__global__ __launch_bounds__(256) void node_kernel(NodeArgs na, int N) {
  int z = blockIdx.y;
  const float* __restrict__ agg = na.agg[z];
  const unsigned short* __restrict__ T = na.T[z];
  const float* __restrict__ bn = na.bn[z];
  unsigned short* __restrict__ U = na.U[z];
  int lane = threadIdx.x & 63;
  int wv = threadIdx.x >> 6;
  int rowbase = blockIdx.x * 256 + wv * 64;
  int l15 = lane & 15, lh = lane >> 4;

  short8 bfr[2][4];
  load_bfrags(na.W[z], bfr, lane);

  f32x4 acc[4][4];
#pragma unroll
  for (int rt = 0; rt < 4; ++rt)
#pragma unroll
    for (int ct = 0; ct < 4; ++ct) acc[rt][ct] = (f32x4){0.f, 0.f, 0.f, 0.f};

#pragma unroll
  for (int rt = 0; rt < 4; ++rt) {
    int row = rowbase + rt * 16 + l15;
    int rc = row < N ? row : 0;
    const fvec4* p = reinterpret_cast<const fvec4*>(agg + (size_t)rc * 64);
#pragma unroll
    for (int ks = 0; ks < 2; ++ks) {
      fvec4 p0 = p[ks * 8 + lh * 2], p1 = p[ks * 8 + lh * 2 + 1];
      short8 ahi = cvt8(p0, p1);
      fvec4 q0, q1;
#pragma unroll
      for (int i = 0; i < 4; ++i) {
        q0[i] = p0[i] - bf2f((unsigned short)ahi[i]);
        q1[i] = p1[i] - bf2f((unsigned short)ahi[i + 4]);
      }
      short8 alo = cvt8(q0, q1);
#pragma unroll
      for (int ct = 0; ct < 4; ++ct) {
        acc[rt][ct] = __builtin_amdgcn_mfma_f32_16x16x32_bf16(ahi, bfr[ks][ct], acc[rt][ct], 0, 0, 0);
        acc[rt][ct] = __builtin_amdgcn_mfma_f32_16x16x32_bf16(alo, bfr[ks][ct], acc[rt][ct], 0, 0, 0);
      }
    }
  }

  float bv[4];
#pragma unroll
  for (int ct = 0; ct < 4; ++ct) bv[ct] = bn[ct * 16 + l15];

#pragma unroll
  for (int rt = 0; rt < 4; ++rt)
#pragma unroll
    for (int rg = 0; rg < 4; ++rg) {
      int row = rowbase + rt * 16 + lh * 4 + rg;
      if (row < N) {
#pragma unroll
        for (int ct = 0; ct < 4; ++ct) {
          int c = ct * 16 + l15;
          float v = acc[rt][ct][rg] + bf2f(T[(size_t)row * 64 + c]) + bv[ct];
          U[(size_t)row * 64 + c] = f2bf(fmaxf(v, 0.0f));
        }
      }
    }
}

// attention over the 2-way stack; 4 threads per node
__global__ __launch_bounds__(256) void attn_kernel(
    const unsigned short* __restrict__ U0, const unsigned short* __restrict__ U1,
    const float* __restrict__ l1w, const float* __restrict__ l1b, const float* __restrict__ l2w,
    float* __restrict__ out, int N) {
  int t = threadIdx.x;
  int node = blockIdx.x * 64 + (t >> 2);
  int q = t & 3;
  if (node >= N) return;
  size_t b0 = (size_t)node * 64;

  float a0[8], a1[8];
#pragma unroll
  for (int i = 0; i < 8; ++i) { a0[i] = l1b[q * 8 + i]; a1[i] = a0[i]; }

  for (int k = 0; k < 64; ++k) {
    float u0 = bf2f(U0[b0 + k]);
    float u1 = bf2f(U1[b0 + k]);
#pragma unroll
    for (int i = 0; i < 8; ++i) {
      float w = l1w[k * 32 + q * 8 + i];
      a0[i] += u0 * w;
      a1[i] += u1 * w;
    }
  }
  float w0 = 0.f, w1 = 0.f;
#pragma unroll
  for (int i = 0; i < 8; ++i) {
    float l2 = l2w[q * 8 + i];
    w0 += tanhf(a0[i]) * l2;
    w1 += tanhf(a1[i]) * l2;
  }
  w0 += __shfl_xor(w0, 1, 4); w0 += __shfl_xor(w0, 2, 4);
  w1 += __shfl_xor(w1, 1, 4); w1 += __shfl_xor(w1, 2, 4);

  float m = fmaxf(w0, w1);
  float e0 = expf(w0 - m), e1 = expf(w1 - m);
  float inv = 1.0f / (e0 + e1);
  float be0 = e0 * inv, be1 = e1 * inv;

#pragma unroll
  for (int j = 0; j < 16; ++j) {
    int c = q * 16 + j;
    out[b0 + c] = be0 * bf2f(U0[b0 + c]) + be1 * bf2f(U1[b0 + c]);
  }
}

static inline size_t au(size_t x) { return (x + 255) & ~(size_t)255; }

extern "C" void kernel_launch(void* const* d_in, const int* in_sizes, int n_in,
                              void* d_out, int out_size, void* d_ws, size_t ws_size,
                              hipStream_t stream) {
  const float* h      = (const float*)d_in[0];
  const float* e_od   = (const float*)d_in[1];
  const float* e_ad   = (const float*)d_in[2];
  const int* src_od   = (const int*)d_in[3];
  const int* dst_od   = (const int*)d_in[4];
  const int* src_ad   = (const int*)d_in[5];
  const int* dst_ad   = (const int*)d_in[6];
  const float* W_src  = (const float*)d_in[7];
  const float* W_dst  = (const float*)d_in[8];
  const float* W_edge = (const float*)d_in[9];
  const float* b_msg  = (const float*)d_in[10];
  const float* W_self = (const float*)d_in[11];
  const float* W_agg  = (const float*)d_in[12];
  const float* b_node = (const float*)d_in[13];
  const float* l1w    = (const float*)d_in[14];
  const float* l1b    = (const float*)d_in[15];
  const float* l2w    = (const float*)d_in[16];
  float* out = (float*)d_out;

  int N = in_sizes[0] / 64;
  int E = in_sizes[1] / 64;
  int NB = (N + 1023) / 1024;

  char* ws = (char*)d_ws;
  size_t off = 0;
  int* counts = (int*)(ws + off);           off += au((size_t)2 * N * sizeof(int));
  float* agg0 = (float*)(ws + off);         off += (size_t)N * 64 * sizeof(float);
  float* agg1 = (float*)(ws + off);         off += (size_t)N * 64 * sizeof(float);
  size_t zero_bytes = off;                  // counts + agg0 + agg1 contiguous
  int* cursor = (int*)(ws + off);           off += au((size_t)2 * N * sizeof(int));
  int* bsum   = (int*)(ws + off);           off += au((size_t)2 * NB * sizeof(int));
  int* el0 = (int*)(ws + off);              off += au((size_t)E * sizeof(int));
  int* el1 = (int*)(ws + off);              off += au((size_t)E * sizeof(int));
  int2* sd0 = (int2*)(ws + off);            off += au((size_t)E * sizeof(int2));
  int2* sd1 = (int2*)(ws + off);            off += au((size_t)E * sizeof(int2));
  size_t NP = au((size_t)N * 64 * sizeof(unsigned short));
  unsigned short* Psrc0 = (unsigned short*)(ws + off); off += NP;
  unsigned short* Pdst0 = (unsigned short*)(ws + off); off += NP;
  unsigned short* Psrc1 = (unsigned short*)(ws + off); off += NP;
  unsigned short* Pdst1 = (unsigned short*)(ws + off); off += NP;
  unsigned short* T0    = (unsigned short*)(ws + off); off += NP;
  unsigned short* T1    = (unsigned short*)(ws + off); off += NP;
  unsigned short* U0 = Psrc0;  // dead after edge pass of graph 0
  unsigned short* U1 = Psrc1;  // dead after edge pass of graph 1

  hipMemsetAsync(ws, 0, zero_bytes, stream);

  int nb = (N + 255) / 256;
  ProjArgs pa;
  pa.W[0] = W_src;         pa.out[0] = Psrc0;
  pa.W[1] = W_dst;         pa.out[1] = Pdst0;
  pa.W[2] = W_src + 4096;  pa.out[2] = Psrc1;
  pa.W[3] = W_dst + 4096;  pa.out[3] = Pdst1;
  pa.W[4] = W_self;        pa.out[4] = T0;
  pa.W[5] = W_self + 4096; pa.out[5] = T1;
  proj_all_kernel<<<nb, 256, 0, stream>>>(h, pa, N);

  int g2e = (2 * E + 255) / 256;
  hist_kernel<<<g2e, 256, 0, stream>>>(dst_od, dst_ad, counts, E, N);
  scan1_kernel<<<dim3(NB, 2), 1024, 0, stream>>>(counts, cursor, bsum, N, NB);
  scan2_kernel<<<2, 1024, 0, stream>>>(bsum, NB);
  scan3_kernel<<<dim3(nb, 2), 256, 0, stream>>>(cursor, bsum, N, NB);
  scatter_kernel<<<g2e, 256, 0, stream>>>(src_od, dst_od, src_ad, dst_ad, cursor,
                                          el0, sd0, el1, sd1, E, N);

  int tiles = (E + 63) / 64;
  int eb = (tiles + 3) / 4;
  edge_sorted_kernel<<<eb, 256, 0, stream>>>(e_od, el0, sd0, W_edge, b_msg,
                                             Psrc0, Pdst0, agg0, E);
  edge_sorted_kernel<<<eb, 256, 0, stream>>>(e_ad, el1, sd1, W_edge + 4096, b_msg + 64,
                                             Psrc1, Pdst1, agg1, E);

  NodeArgs na;
  na.agg[0] = agg0; na.T[0] = T0; na.W[0] = W_agg;        na.bn[0] = b_node;      na.U[0] = U0;
  na.agg[1] = agg1; na.T[1] = T1; na.W[1] = W_agg + 4096; na.bn[1] = b_node + 64; na.U[1] = U1;
  node_kernel<<<dim3(nb, 2), 256, 0, stream>>>(na, N);

  attn_kernel<<<(N + 63) / 64, 256, 0, stream>>>(U0, U1, l1w, l1b, l2w, out, N);
}